// Round 1
// baseline (235.841 us; speedup 1.0000x reference)
//
#include <hip/hip_runtime.h>

// LIF neuron forward: T=8 timesteps, x shape [T*B, C, H, W] = [256,128,32,32] f32.
// Recurrence per spatial element (independent across B,C,H,W):
//   mem = beta*mem + (1-beta)*x_t ; spike = (mem >= 0.3*Vth)*Vth ;
//   mem -= spike ; out_t = spike/0.05
//
// History:
//  R1: 1 float4/thread one-shot: 87 us, ~3.0 TB/s CU-side. Pipes idle.
//  R3: nt stores: 100 us (reverted). R4/R5: asm pins defeated/no effect.
//  R6: grid-stride x4, occupancy 62->31%: 94 us. Occupancy-insensitive.
//  R7: 2 contiguous cols/thread: 82 us. R8: K_COLS=8 interleaved, 32 KB
//      block bursts: 79.5 us. Burst length was the only lever that moved.
//  R9 (this): whole-kernel read burst. Diagnosis: per-timestep phase cycle
//      (load->drain->compute->store) + tight register reuse (36 VGPRs) kept
//      time-averaged read MLP at ~2 KB/CU (Little's law from 2.53 TB/s HBM
//      @ ~800cy latency) -> reads latency-bound at half of copy BW.
//      Now: each thread loads ALL 16 float4 (2 cols x 8 t) up front into
//      distinct registers (asm-pinned so the compiler can't sink them),
//      then computes t=0..7 writing spikes INTO the xv registers and storing
//      from them. Store data regs are never redefined after their store ->
//      no vmcnt waits on stores ever; loads are one streaming burst
//      (~16 KB/wave, ~256 KB/CU in flight) -> reads go BW-bound.
//
// Bit-exactness notes (decisions flip 0<->20, zero flips allowed):
//  - beta = f32(exp(f32(-0.05))) = 0x1.E7078Cp-1 (correctly rounded; verified
//    absmax 0.0 in R1/R3/R4/R5/R6/R7/R8).
//  - mem update uses __fmul_rn/__fadd_rn to forbid FMA contraction (numpy
//    evaluates beta*mem and (1-beta)*xt as separate rn-multiplies + rn-add).
//  - (1.0f - beta) exact; Vth clamp round-trips to 1.0f; vth/0.05f == 20.0f.

#define T_STEPS 8
#define S_ELEMS (32 * 128 * 32 * 32)   // per-timestep elements = 4,194,304
#define S4 (S_ELEMS / 4)               // float4 per timestep = 1,048,576
#define BLOCK 256
#define K_COLS 2                       // interleaved columns per thread
#define GRID (S4 / (BLOCK * K_COLS))   // 2048 blocks = 8 blocks/CU

typedef float f32x4 __attribute__((ext_vector_type(4)));

__global__ __launch_bounds__(BLOCK) void lif_fwd_kernel(
    const f32x4* __restrict__ x, const float* __restrict__ vth_ptr,
    f32x4* __restrict__ out) {
  // Block covers BLOCK*K_COLS consecutive float4 per plane; thread handles
  // columns base + k*BLOCK so every load/store inst is a coalesced 1-KB
  // wave access.
  const int base = blockIdx.x * (BLOCK * K_COLS) + threadIdx.x;

  // Vth clamp (no-grad): relu(Vth - 5e-4) + 5e-4, all f32 rn. (scalar path)
  const float vth_raw = vth_ptr[0];
  const float vth = __fadd_rn(fmaxf(__fsub_rn(vth_raw, 0.0005f), 0.0f), 0.0005f);
  const float thr = __fmul_rn(0.3f, vth);      // ALPHA * Vth
  const float outval = __fdiv_rn(vth, 0.05f);  // Vth / DELTA_T (== 20.0f)

  const float beta = 0x1.E7078Cp-1f;        // f32(exp(f32(-0.05)))
  const float omb = __fsub_rn(1.0f, beta);  // exact

  // === Whole-kernel read burst: 16 loads (2 cols x 8 timesteps) into
  // distinct registers. Issued back-to-back; nothing depends on them yet.
  f32x4 xv[T_STEPS][K_COLS];
#pragma unroll
  for (int t = 0; t < T_STEPS; ++t) {
#pragma unroll
    for (int k = 0; k < K_COLS; ++k) {
      xv[t][k] = x[base + k * BLOCK + (size_t)t * S4];
    }
  }

  // Pin every loaded value live here so the compiler cannot sink late-t
  // loads below early-t stores to shrink register pressure. (Costs one
  // vmcnt(0) drain of the read burst before compute -- compute is ~2% of
  // kernel time, and it buys a clean all-reads-first VMEM queue.)
#pragma unroll
  for (int t = 0; t < T_STEPS; ++t) {
#pragma unroll
    for (int k = 0; k < K_COLS; ++k) {
      asm volatile("" : "+v"(xv[t][k]));
    }
  }

  float m[K_COLS * 4];
#pragma unroll
  for (int j = 0; j < K_COLS * 4; ++j) m[j] = 0.0f;

#pragma unroll
  for (int t = 0; t < T_STEPS; ++t) {
#pragma unroll
    for (int k = 0; k < K_COLS; ++k) {
#pragma unroll
      for (int c = 0; c < 4; ++c) {
        const float mm =
            __fadd_rn(__fmul_rn(beta, m[k * 4 + c]), __fmul_rn(omb, xv[t][k][c]));
        const bool s = (mm >= thr);
        // Overwrite the input register with the spike output: the store
        // below is the LAST use of xv[t][k], so no s_waitcnt is ever
        // needed on any store (its data reg is never redefined).
        xv[t][k][c] = s ? outval : 0.0f;
        m[k * 4 + c] = s ? __fsub_rn(mm, vth) : mm;
      }
      out[base + k * BLOCK + (size_t)t * S4] = xv[t][k];
    }
  }
}

extern "C" void kernel_launch(void* const* d_in, const int* in_sizes, int n_in,
                              void* d_out, int out_size, void* d_ws,
                              size_t ws_size, hipStream_t stream) {
  const f32x4* x = (const f32x4*)d_in[0];
  const float* vth = (const float*)d_in[1];
  f32x4* out = (f32x4*)d_out;
  lif_fwd_kernel<<<GRID, BLOCK, 0, stream>>>(x, vth, out);
}

// Round 2
// 234.762 us; speedup vs baseline: 1.0046x; 1.0046x over previous
//
#include <hip/hip_runtime.h>

// LIF neuron forward: T=8 timesteps, x shape [T*B, C, H, W] = [256,128,32,32] f32.
// Recurrence per spatial element (independent across B,C,H,W):
//   mem = beta*mem + (1-beta)*x_t ; spike = (mem >= 0.3*Vth)*Vth ;
//   mem -= spike ; out_t = spike/0.05
//
// History:
//  R1: 1 float4/thread one-shot: 87 us, ~3.0 TB/s CU-side. Pipes idle.
//  R3: nt stores: 100 us (reverted). R4/R5: asm pins defeated/no effect.
//  R6: grid-stride x4, occupancy 62->31%: 94 us. Occupancy-insensitive.
//  R7: 2 contiguous cols/thread: 82 us. R8: K_COLS=8 interleaved, 32 KB
//      block bursts: 79.5 us. Burst length was the only lever that moved.
//  R9: whole-kernel read burst via 16 SEPARATE asm pins: DEFEATED again
//      (VGPR_Count=40 proves loads were not kept live; LLVM sank each load
//      to its own pin and hoisted stores between pins). 84-90 us.
//  R10 (this): ONE asm statement with all 16 float4 as "+v" operands.
//      All 64 load-dest VGPRs must be simultaneously live at that point ->
//      loads cannot sink, stores cannot hoist above. vmcnt FIFO becomes
//      16 loads then 16 wait-free stores (spike written INTO xv reg; store
//      is its last use, so no store-data reg is ever redefined -> zero
//      s_waitcnt on stores). ~16 KB reads in flight per wave, ~200 KB/CU.
//      Verification signal: VGPR_Count must jump to ~100+; if it is still
//      ~40 the pin was defeated and the theory is untested.
//
// Bit-exactness notes (decisions flip 0<->20, zero flips allowed):
//  - beta = f32(exp(f32(-0.05))) = 0x1.E7078Cp-1 (correctly rounded; verified
//    absmax 0.0 in R1..R9).
//  - mem update uses __fmul_rn/__fadd_rn to forbid FMA contraction (numpy
//    evaluates beta*mem and (1-beta)*xt as separate rn-multiplies + rn-add).
//  - (1.0f - beta) exact; Vth clamp round-trips to 1.0f; vth/0.05f == 20.0f.

#define T_STEPS 8
#define S_ELEMS (32 * 128 * 32 * 32)   // per-timestep elements = 4,194,304
#define S4 (S_ELEMS / 4)               // float4 per timestep = 1,048,576
#define BLOCK 256
#define K_COLS 2                       // interleaved columns per thread
#define GRID (S4 / (BLOCK * K_COLS))   // 2048 blocks = 8 blocks/CU

typedef float f32x4 __attribute__((ext_vector_type(4)));

__global__ __launch_bounds__(BLOCK) void lif_fwd_kernel(
    const f32x4* __restrict__ x, const float* __restrict__ vth_ptr,
    f32x4* __restrict__ out) {
  // Block covers BLOCK*K_COLS consecutive float4 per plane; thread handles
  // columns base + k*BLOCK so every load/store inst is a coalesced 1-KB
  // wave access.
  const int base = blockIdx.x * (BLOCK * K_COLS) + threadIdx.x;

  // Vth clamp (no-grad): relu(Vth - 5e-4) + 5e-4, all f32 rn. (scalar path)
  const float vth_raw = vth_ptr[0];
  const float vth = __fadd_rn(fmaxf(__fsub_rn(vth_raw, 0.0005f), 0.0f), 0.0005f);
  const float thr = __fmul_rn(0.3f, vth);      // ALPHA * Vth
  const float outval = __fdiv_rn(vth, 0.05f);  // Vth / DELTA_T (== 20.0f)

  const float beta = 0x1.E7078Cp-1f;        // f32(exp(f32(-0.05)))
  const float omb = __fsub_rn(1.0f, beta);  // exact

  // === Whole-kernel read burst: 16 loads (2 cols x 8 timesteps) into
  // distinct registers. Issued back-to-back; nothing depends on them yet.
  f32x4 xv[T_STEPS][K_COLS];
#pragma unroll
  for (int t = 0; t < T_STEPS; ++t) {
#pragma unroll
    for (int k = 0; k < K_COLS; ++k) {
      xv[t][k] = x[base + k * BLOCK + (size_t)t * S4];
    }
  }

  // ONE pin with ALL 16 values: forces all 64 load-dest VGPRs live here
  // simultaneously. Loads can sink at most to this point (still above all
  // compute/stores); stores (data-dependent on asm outputs) cannot hoist
  // above it. Costs one vmcnt(0) drain of the read burst before compute --
  // compute is ~2% of kernel time, and cross-wave overlap (14 waves/CU)
  // covers it; buys an all-reads-first VMEM queue with wait-free stores.
  asm volatile(""
               : "+v"(xv[0][0]), "+v"(xv[0][1]), "+v"(xv[1][0]), "+v"(xv[1][1]),
                 "+v"(xv[2][0]), "+v"(xv[2][1]), "+v"(xv[3][0]), "+v"(xv[3][1]),
                 "+v"(xv[4][0]), "+v"(xv[4][1]), "+v"(xv[5][0]), "+v"(xv[5][1]),
                 "+v"(xv[6][0]), "+v"(xv[6][1]), "+v"(xv[7][0]), "+v"(xv[7][1]));

  float m[K_COLS * 4];
#pragma unroll
  for (int j = 0; j < K_COLS * 4; ++j) m[j] = 0.0f;

#pragma unroll
  for (int t = 0; t < T_STEPS; ++t) {
#pragma unroll
    for (int k = 0; k < K_COLS; ++k) {
#pragma unroll
      for (int c = 0; c < 4; ++c) {
        const float mm =
            __fadd_rn(__fmul_rn(beta, m[k * 4 + c]), __fmul_rn(omb, xv[t][k][c]));
        const bool s = (mm >= thr);
        // Overwrite the input register with the spike output: the store
        // below is the LAST use of xv[t][k], so no s_waitcnt is ever
        // needed on any store (its data reg is never redefined).
        xv[t][k][c] = s ? outval : 0.0f;
        m[k * 4 + c] = s ? __fsub_rn(mm, vth) : mm;
      }
      out[base + k * BLOCK + (size_t)t * S4] = xv[t][k];
    }
  }
}

extern "C" void kernel_launch(void* const* d_in, const int* in_sizes, int n_in,
                              void* d_out, int out_size, void* d_ws,
                              size_t ws_size, hipStream_t stream) {
  const f32x4* x = (const f32x4*)d_in[0];
  const float* vth = (const float*)d_in[1];
  f32x4* out = (f32x4*)d_out;
  lif_fwd_kernel<<<GRID, BLOCK, 0, stream>>>(x, vth, out);
}